// Round 1
// baseline (3991.126 us; speedup 1.0000x reference)
//
#include <hip/hip_runtime.h>

// TiThTe: sequential 3-state thermal RC scan, B=4096 elements, T=8760 steps.
// Round 1: numerically exact version — mirrors numpy fp32 op order exactly.
//  - correctly-rounded fp32 div/sqrt (hipcc default, no fast-math)
//  - fp contract OFF so no FMA fusion perturbs rounding vs numpy
//  - only hoist: k2 = dtf/C2 (same fp op every iteration -> bit-identical)
// One thread per batch element; 64-thread blocks -> 64 waves on 64 CUs.
// This is latency-bound on the per-step dependent chain; later rounds will
// shorten the chain (reciprocals / fused linear coeffs / rsqrt) if the
// absmax threshold tolerates it.

__global__ __launch_bounds__(64) void tithte_kernel(
    const float* __restrict__ state0,   // (B,3)
    const float* __restrict__ params,   // (B,6) : C1,R1,C2,R2,C3,R3
    const float* __restrict__ ext,      // (T,3) : T_out, heatPower, solarGains
    const int*   __restrict__ dtp,      // scalar dt
    float*       __restrict__ out,      // (T,B,3)
    int B, int T)
{
#pragma clang fp contract(off)
    const int b = blockIdx.x * blockDim.x + threadIdx.x;
    if (b >= B) return;

    const float dtf = (float)dtp[0];

    const float C1 = params[b * 6 + 0];
    const float R1 = params[b * 6 + 1];
    const float C2 = params[b * 6 + 2];
    const float R2 = params[b * 6 + 3];
    const float C3 = params[b * 6 + 4];
    const float R3 = params[b * 6 + 5];

    float Tin  = state0[b * 3 + 0];
    float Th   = state0[b * 3 + 1];
    float Tenv = state0[b * 3 + 2];

    // dtf / C2 is the identical fp operation every step -> safe exact hoist.
    const float k2 = dtf / C2;

    const float TAME  = 100000.0f;
    const float TAME2 = 100000.0f * 100000.0f;  // 1e10, exact in fp32

    float* op = out + (size_t)b * 3;
    const size_t ostride = (size_t)B * 3;

    for (int t = 0; t < T; ++t) {
        const float Tout = ext[t * 3 + 0];
        const float hp   = ext[t * 3 + 1];
        const float sg   = ext[t * 3 + 2];

        // exact numpy op order:
        const float P1 = (Tin - Tenv) / R1;          // P_in2Wall
        const float P2 = (Tin - Th)   / R2;          // P_in2Heater
        float dTin  = ((sg - P1 - P2) * dtf) / C1;
        float dTh   = k2 * (hp + P2);
        float dTenv = ((P1 + (Tout - Tenv) / R3) * dtf) / C3;

        // tame(x) = x*TAME / sqrt(x*x + TAME*TAME), exact order
        dTin  = (dTin  * TAME) / sqrtf(dTin  * dTin  + TAME2);
        dTh   = (dTh   * TAME) / sqrtf(dTh   * dTh   + TAME2);
        dTenv = (dTenv * TAME) / sqrtf(dTenv * dTenv + TAME2);

        Tin  += dTin;
        Th   += dTh;
        Tenv += dTenv;

        op[0] = Tin;
        op[1] = Th;
        op[2] = Tenv;
        op += ostride;
    }
}

extern "C" void kernel_launch(void* const* d_in, const int* in_sizes, int n_in,
                              void* d_out, int out_size, void* d_ws, size_t ws_size,
                              hipStream_t stream) {
    const float* state0 = (const float*)d_in[0];
    const float* params = (const float*)d_in[1];
    const float* ext    = (const float*)d_in[2];
    const int*   dtp    = (const int*)d_in[3];
    float*       out    = (float*)d_out;

    const int B = in_sizes[0] / 3;   // 4096
    const int T = in_sizes[2] / 3;   // 8760

    const int block = 64;
    const int grid  = (B + block - 1) / block;
    tithte_kernel<<<grid, block, 0, stream>>>(state0, params, ext, dtp, out, B, T);
}

// Round 2
// 2230.769 us; speedup vs baseline: 1.7891x; 1.7891x over previous
//
#include <hip/hip_runtime.h>

// TiThTe: sequential 3-state thermal RC scan, B=4096 elements, T=8760 steps.
// Round 2: kill the per-step VMEM round-trip.
//   R1 post-mortem: 1000 cyc/step, VALUBusy 4.3% -> ~950 stall cyc/step.
//   Cause: per-iter global load of ext sits in the dependent chain, and its
//   vmcnt wait also drains the 3 just-issued HBM stores (shared counter).
// Changes:
//   - ext staged into LDS in chunks of 2190 steps (26 KB): hot loop has ZERO
//     VMEM loads -> stores are fire-and-forget, no vmcnt waits in the chain.
//   - #pragma unroll 4 so the compiler hoists/pipelines the ds_reads.
//   - hoisted reciprocals: 1/R1, 1/R2, 1/R3, dtf/C1, dtf/C3 (5 divs -> muls).
//     ulp-level numeric change; tame kept bit-exact (contract off, sqrtf,
//     true divide) to stay under the absmax threshold (R1 floor was 1024/3891).
// One thread per batch element; 64 blocks x 64 threads -> 1 wave on 64 CUs.

#define CHUNK 2190   // 8760 = 4 * 2190; 2190*3*4 B = 26,280 B LDS

__global__ __launch_bounds__(64) void tithte_kernel(
    const float* __restrict__ state0,   // (B,3)
    const float* __restrict__ params,   // (B,6) : C1,R1,C2,R2,C3,R3
    const float* __restrict__ ext,      // (T,3) : T_out, heatPower, solarGains
    const int*   __restrict__ dtp,      // scalar dt
    float*       __restrict__ out,      // (T,B,3)
    int B, int T)
{
#pragma clang fp contract(off)
    __shared__ float sext[CHUNK * 3];

    const int b = blockIdx.x * blockDim.x + threadIdx.x;

    const float dtf = (float)dtp[0];

    const float C1 = params[b * 6 + 0];
    const float R1 = params[b * 6 + 1];
    const float C2 = params[b * 6 + 2];
    const float R2 = params[b * 6 + 3];
    const float C3 = params[b * 6 + 4];
    const float R3 = params[b * 6 + 5];

    // Hoisted combined coefficients (ulp-level change vs per-step divides).
    const float rR1 = 1.0f / R1;
    const float rR2 = 1.0f / R2;
    const float rR3 = 1.0f / R3;
    const float k1  = dtf / C1;
    const float k2  = dtf / C2;
    const float k3  = dtf / C3;

    float Tin  = state0[b * 3 + 0];
    float Th   = state0[b * 3 + 1];
    float Tenv = state0[b * 3 + 2];

    const float TAME  = 100000.0f;
    const float TAME2 = 100000.0f * 100000.0f;  // 1e10, exact in fp32

    float* op = out + (size_t)b * 3;
    const size_t ostride = (size_t)B * 3;

    for (int c = 0; c < T; c += CHUNK) {
        const int n = (T - c < CHUNK) ? (T - c) : CHUNK;

        __syncthreads();   // previous chunk's LDS reads done before overwrite
        for (int i = threadIdx.x; i < n * 3; i += 64)
            sext[i] = ext[(size_t)c * 3 + i];
        __syncthreads();

#pragma unroll 4
        for (int t = 0; t < n; ++t) {
            const float Tout = sext[t * 3 + 0];
            const float hp   = sext[t * 3 + 1];
            const float sg   = sext[t * 3 + 2];

            const float P1 = (Tin - Tenv) * rR1;      // P_in2Wall
            const float P2 = (Tin - Th)   * rR2;      // P_in2Heater
            float dTin  = (sg - P1 - P2) * k1;
            float dTh   = k2 * (hp + P2);
            float dTenv = (P1 + (Tout - Tenv) * rR3) * k3;

            // tame(x) = x*TAME / sqrt(x*x + TAME*TAME) — exact np order
            dTin  = (dTin  * TAME) / sqrtf(dTin  * dTin  + TAME2);
            dTh   = (dTh   * TAME) / sqrtf(dTh   * dTh   + TAME2);
            dTenv = (dTenv * TAME) / sqrtf(dTenv * dTenv + TAME2);

            Tin  += dTin;
            Th   += dTh;
            Tenv += dTenv;

            op[0] = Tin;
            op[1] = Th;
            op[2] = Tenv;
            op += ostride;
        }
    }
}

extern "C" void kernel_launch(void* const* d_in, const int* in_sizes, int n_in,
                              void* d_out, int out_size, void* d_ws, size_t ws_size,
                              hipStream_t stream) {
    const float* state0 = (const float*)d_in[0];
    const float* params = (const float*)d_in[1];
    const float* ext    = (const float*)d_in[2];
    const int*   dtp    = (const int*)d_in[3];
    float*       out    = (float*)d_out;

    const int B = in_sizes[0] / 3;   // 4096
    const int T = in_sizes[2] / 3;   // 8760

    const int block = 64;
    const int grid  = B / block;     // 64 blocks, B is a multiple of 64
    tithte_kernel<<<grid, block, 0, stream>>>(state0, params, ext, dtp, out, B, T);
}